// Round 8
// baseline (509.911 us; speedup 1.0000x reference)
//
#include <hip/hip_runtime.h>
#include <stdint.h>

#define B_   8
#define C_   1024
#define HW_  4096
#define K_   64
#define NPIX (B_*HW_)
#define SLAB ((size_t)B_*K_*C_)
#define NSEG 8

typedef __attribute__((ext_vector_type(8))) short short8;
typedef __attribute__((ext_vector_type(4))) float f32x4;

__device__ __forceinline__ uint16_t f2bf(float f) {
  uint32_t u = __float_as_uint(f);
  u += 0x7fffu + ((u >> 16) & 1u);   // round-to-nearest-even
  return (uint16_t)(u >> 16);
}

// async global -> LDS, 16B per lane. LDS dest must be wave-uniform base; lane deposits at base+lane*16.
__device__ __forceinline__ void gl2lds16(const uint16_t* g, uint16_t* l) {
  __builtin_amdgcn_global_load_lds(
      (const __attribute__((address_space(1))) unsigned int*)(g),
      (__attribute__((address_space(3))) unsigned int*)(l), 16, 0, 0);
}

// ---------- prep: normalized centroids, transposed gT[c][n] ----------
__global__ void prep_gT(const float* __restrict__ g, float* __restrict__ gT) {
  int n = blockIdx.x;            // 64 blocks
  int t = threadIdx.x;           // 256 threads
  float vals[4]; float ss = 0.f;
  #pragma unroll
  for (int i = 0; i < 4; i++) { float v = g[n*C_ + t + i*256]; vals[i] = v; ss += v*v; }
  __shared__ float red[256];
  red[t] = ss; __syncthreads();
  for (int s = 128; s > 0; s >>= 1) { if (t < s) red[t] += red[t+s]; __syncthreads(); }
  float scale = 1.f / fmaxf(sqrtf(red[0]), 1e-12f);
  #pragma unroll
  for (int i = 0; i < 4; i++) gT[(t + i*256)*K_ + n] = vals[i]*scale;
}

// ---------- prep: fc_weight fp32 -> bf16 row-major [o][c], 4 elems/thread ----------
__global__ void prep_wb(const float* __restrict__ w, uint16_t* __restrict__ wb) {
  int i = blockIdx.x*256 + threadIdx.x;   // 1024 blocks
  float4 v = *(const float4*)&w[i*4];
  uint16_t o[4] = {f2bf(v.x), f2bf(v.y), f2bf(v.z), f2bf(v.w)};
  *(uint64_t*)&wb[i*4] = *(const uint64_t*)o;
}

// ---------- pass A: argmax_n (x . g_n), fp32, + counts ----------
// Register-staged LDS tile (R6): each thread loads 2 float4s issued before the
// 512-FMA compute (HBM latency hides under it), ds_writes to the back buffer
// after compute, one barrier per chunk. FMA order ascending -> bitwise-identical.
__launch_bounds__(256)
__global__ void pass_assign(const float* __restrict__ x, const float* __restrict__ gT,
                            int* __restrict__ idx, int* __restrict__ count) {
  int bb = blockIdx.x >> 6;      // grid 512 = 8 b * 64 ptiles
  int pt = blockIdx.x & 63;
  int t = threadIdx.x;
  int lane = t & 63;
  int w = t >> 6;
  int ng = __builtin_amdgcn_readfirstlane(w);  // wave id = n-group (uniform -> s_loads of g)
  __shared__ alignas(16) float xs[2][32][64];  // 2 x 8 KB staging
  const float* xb = x + (size_t)bb*C_*HW_ + pt*64;
  const float* gp = gT + ng*16;

  int r0 = t >> 4;               // c-row within chunk for slot t   (0..15)
  int q0 = t & 15;               // float4 group within 64-px row   (0..15)
  const float* p0 = xb + (size_t)r0*HW_ + q0*4;   // slot t      -> xs[.][r0][q0*4]
  const float* p1 = p0 + (size_t)16*HW_;          // slot t+256  -> xs[.][r0+16][q0*4]

  float acc[16];
  #pragma unroll
  for (int n = 0; n < 16; n++) acc[n] = 0.f;

  {
    float4 v0 = *(const float4*)p0;
    float4 v1 = *(const float4*)p1;
    *(float4*)&xs[0][r0][q0*4]    = v0;
    *(float4*)&xs[0][r0+16][q0*4] = v1;
  }
  __syncthreads();               // chunk 0 staged
  for (int cc = 0; cc < 32; cc++) {
    int cur = cc & 1;
    float4 n0, n1;
    if (cc + 1 < 32) {           // issue next chunk's loads; land under the FMAs
      n0 = *(const float4*)(p0 + (size_t)(cc + 1)*32*HW_);
      n1 = *(const float4*)(p1 + (size_t)(cc + 1)*32*HW_);
    }
    #pragma unroll 16
    for (int ci = 0; ci < 32; ci++) {
      float xv = xs[cur][ci][lane];
      const float* gr = gp + (cc*32 + ci)*K_;    // wave-uniform -> s_load
      #pragma unroll
      for (int n2 = 0; n2 < 16; n2++) acc[n2] = fmaf(xv, gr[n2], acc[n2]);
    }
    if (cc + 1 < 32) {           // write-late into the back buffer
      *(float4*)&xs[cur^1][r0][q0*4]    = n0;    // cur^1 last read before the
      *(float4*)&xs[cur^1][r0+16][q0*4] = n1;    // barrier that ended step cc-1
    }
    __syncthreads();             // writes visible; all waves done reading cur
  }

  float best = acc[0]; int bi = 0;
  #pragma unroll
  for (int n = 1; n < 16; n++) { if (acc[n] > best) { best = acc[n]; bi = n; } }
  __shared__ float bv[4][64];
  __shared__ int   bn[4][64];
  __shared__ int   hist[64];
  if (t < 64) hist[t] = 0;
  bv[w][lane] = best; bn[w][lane] = ng*16 + bi;
  __syncthreads();
  if (t < 64) {
    float mv = bv[0][t]; int mn = bn[0][t];
    #pragma unroll
    for (int wv2 = 1; wv2 < 4; wv2++) { if (bv[wv2][t] > mv) { mv = bv[wv2][t]; mn = bn[wv2][t]; } }
    idx[bb*HW_ + pt*64 + t] = mn;
    atomicAdd(&hist[mn], 1);
  }
  __syncthreads();
  if (t < 64 && hist[t] > 0) atomicAdd(&count[bb*K_ + t], hist[t]);
}

// ---------- pass B: sum_x[b,n,c] partials as a one-hot bf16 MFMA GEMM ----------
// D[c][n] = sum_p X[c][p] * onehot[p][n]. No LDS, no atomics.
// grid 1024 = 8 b * 16 ctiles(64 rows) * 8 psegs(512 pixels).
__launch_bounds__(256)
__global__ void pass_bins(const float* __restrict__ x, const int* __restrict__ idx,
                          float* __restrict__ sumxp) {
  int bid = blockIdx.x;
  int ps = bid & 7;              // pixel segment (512 pixels)
  int ct = (bid >> 3) & 15;      // c tile (64 rows)
  int bb = bid >> 7;             // batch
  int t = threadIdx.x;
  int lane = t & 63;
  int w = t >> 6;                // wave -> 16 c-rows
  int col = lane & 15;
  int kg  = lane >> 4;           // k-group: 8 consecutive pixels per lane
  int crow = ct*64 + w*16 + col;
  const float* xp = x + (size_t)bb*C_*HW_ + (size_t)crow*HW_ + ps*512 + kg*8;
  const int*   ip = idx + bb*HW_ + ps*512 + kg*8;

  const f32x4 fzero = {0.f, 0.f, 0.f, 0.f};
  f32x4 acc[4];
  #pragma unroll
  for (int f = 0; f < 4; f++) acc[f] = fzero;

  for (int ks = 0; ks < 16; ks++) {
    // A: 8 consecutive pixels of this c-row, fp32 -> bf16
    float a0[8];
    *(float4*)&a0[0] = *(const float4*)&xp[ks*32];
    *(float4*)&a0[4] = *(const float4*)&xp[ks*32 + 4];
    short8 af;
    #pragma unroll
    for (int j = 0; j < 8; j++) af[j] = (short)f2bf(a0[j]);
    // cluster ids of those 8 pixels (same 32B broadcast across a 16-lane group)
    int iv8[8];
    *(int4*)&iv8[0] = *(const int4*)&ip[ks*32];
    *(int4*)&iv8[4] = *(const int4*)&ip[ks*32 + 4];
    // 4 one-hot B frags cover n = 0..63 (bf16 1.0 = 0x3F80, exact)
    #pragma unroll
    for (int f = 0; f < 4; f++) {
      int n = f*16 + col;
      short8 bfrag;
      #pragma unroll
      for (int j = 0; j < 8; j++) bfrag[j] = (short)((iv8[j] == n) ? 0x3F80 : 0);
      acc[f] = __builtin_amdgcn_mfma_f32_16x16x32_bf16(af, bfrag, acc[f], 0, 0, 0);
    }
  }
  // C/D layout: col = lane&15 (-> n within frag), row = (lane>>4)*4 + reg (-> c-row)
  #pragma unroll
  for (int f = 0; f < 4; f++) {
    int n = f*16 + col;
    size_t base = (size_t)ps*SLAB + ((size_t)bb*K_ + n)*C_ + ct*64 + w*16 + kg*4;
    *(f32x4*)&sumxp[base] = acc[f];   // 16B aligned; lanes of one n fill a 64B line
  }
}

// ---------- pass B2: c_local, c_localT, ||c||^2 (sums the 8 pixel-segment slabs) ----------
__launch_bounds__(256)
__global__ void pass_cfinal(const float* __restrict__ sumxp, const int* __restrict__ count,
                            float* __restrict__ cl, float* __restrict__ clT,
                            float* __restrict__ cn2) {
  int bb = blockIdx.x >> 6, n = blockIdx.x & 63, t = threadIdx.x;  // grid 512
  float inv = 1.f / fmaxf((float)count[bb*K_ + n], 1.f);
  float ss = 0.f;
  #pragma unroll
  for (int i = 0; i < 4; i++) {
    int c = t + i*256;
    size_t o = ((size_t)bb*K_ + n)*C_ + c;
    float v = 0.f;
    #pragma unroll
    for (int s = 0; s < NSEG; s++) v += sumxp[o + (size_t)s*SLAB];
    v *= inv;
    cl [((size_t)bb*K_ + n)*C_ + c] = v;
    clT[((size_t)bb*C_ + c)*K_ + n] = v;
    ss += v*v;
  }
  __shared__ float red[256];
  red[t] = ss; __syncthreads();
  for (int s = 128; s > 0; s >>= 1) { if (t < s) red[t] += red[t+s]; __syncthreads(); }
  if (t == 0) cn2[bb*K_ + n] = red[0];
}

// ---------- pass C0: w[p] then x_cal bf16, transposed [pixel][c] ----------
__launch_bounds__(256)
__global__ void pass_xcal(const float* __restrict__ x, const int* __restrict__ idx,
                          const float* __restrict__ cl, const float* __restrict__ clT,
                          const float* __restrict__ cn2, uint16_t* __restrict__ xcal) {
  int bb = blockIdx.x >> 6, pt = blockIdx.x & 63, t = threadIdx.x;  // grid 512: 64-pixel tiles
  int lane = t & 63, cs = t >> 6;
  __shared__ float xT[64][129];
  __shared__ int   widx[64];
  __shared__ float pdot[4][64], pxsq[4][64], wv[64];
  if (t < 64) widx[t] = idx[bb*HW_ + pt*64 + t];
  __syncthreads();
  const float* xb = x + (size_t)bb*C_*HW_ + pt*64;
  // phase 1: direct per-pixel dot; lane = pixel, wave = c-strip. Coalesced x, 256B clT gather rows.
  int myi = widx[lane];
  const float* clb = clT + (size_t)bb*C_*K_ + myi;
  float dp = 0.f, xq = 0.f;
  #pragma unroll 4
  for (int ci = 0; ci < 256; ci++) {
    int c = cs*256 + ci;
    float xv = xb[(size_t)c*HW_ + lane];
    dp = fmaf(xv, clb[(size_t)c*K_], dp);
    xq = fmaf(xv, xv, xq);
  }
  pdot[cs][lane] = dp; pxsq[cs][lane] = xq;
  __syncthreads();
  if (t < 64) {
    float d = pdot[0][t]+pdot[1][t]+pdot[2][t]+pdot[3][t];
    float q = pxsq[0][t]+pxsq[1][t]+pxsq[2][t]+pxsq[3][t];
    float msd = (q - 2.f*d + cn2[bb*K_ + widx[t]]) * (1.f/1024.f);
    wv[t] = expf(-msd);
  }
  __syncthreads();
  // phase 2: transpose-write bf16 [pixel][c] (x tiles re-read; L2-hot from phase 1)
  for (int cc = 0; cc < 8; cc++) {
    #pragma unroll
    for (int i = 0; i < 32; i++) {
      int co = cs*32 + i;
      xT[lane][co] = xb[(size_t)(cc*128 + co)*HW_ + lane];
    }
    __syncthreads();
    #pragma unroll 2
    for (int pp = 0; pp < 16; pp++) {
      int p = pp*4 + cs;
      float wval = wv[p]; int iv = widx[p];
      const float* clr = cl + ((size_t)bb*K_ + iv)*C_ + cc*128;
      size_t obase = ((size_t)(bb*HW_ + pt*64 + p))*C_ + cc*128;
      #pragma unroll
      for (int ci = 0; ci < 2; ci++) {
        int co = ci*64 + lane;
        float xvv = xT[p][co];
        float v = fmaf(wval, clr[co] - xvv, xvv);   // x + w*(c-x)
        xcal[obase + co] = f2bf(v);
      }
    }
    __syncthreads();
  }
}

// ---------- pass C: out = relu(W @ x_cal + bias), bf16 MFMA, one 128x128 tile/block ----------
// R8: 3-stage pipeline at BK=32 with COUNTED vmcnt (T4). Each iteration stages
// tile kb+2 and ends with s_waitcnt vmcnt(4) (tile kb+1's 4 DMAs -- issued a
// full iteration ago -- are the oldest outstanding and must have landed; tile
// kb+2's 4 stay in flight across the barrier) + raw s_barrier. Never drains
// vmcnt(0) in the main loop, so DMA latency spans a whole iteration instead of
// serializing each step. 48 KB LDS -> 3 blocks/CU (was 64 KB / 2). K-slice and
// MFMA order unchanged -> bitwise-identical results.
#define BK2 32
__launch_bounds__(256)
__global__ void gemm_out(const uint16_t* __restrict__ wb, const uint16_t* __restrict__ xcal,
                         const float* __restrict__ bias, float* __restrict__ out) {
  // 48 KB: 3 stages x (W 8KB + X 8KB). Epilogue ep (32 KB) aliases stages 0-1.
  __shared__ alignas(16) uint16_t smem[3*2*128*BK2];
  float* ep = (float*)smem;
  int t = threadIdx.x;
  int lane = t & 63;
  int w = t >> 6, wm = w & 1, wn = w >> 1;
  // XCD swizzle: xcd = bid&7; within an XCD, ot fastest -> 8 blocks sharing an xcal
  // tile run consecutively on the SAME XCD (xcal tile + all 8 W tiles stay L2-hot).
  int g  = blockIdx.x & 7;
  int li = blockIdx.x >> 3;
  int ot = li & 7;
  int qt = g*32 + (li >> 3);

  const uint16_t* wsrc = wb   + (size_t)ot*128*C_;
  const uint16_t* xsrc = xcal + (size_t)qt*128*C_;

  const f32x4 fzero = {0.f, 0.f, 0.f, 0.f};
  f32x4 acc[4][4];
  #pragma unroll
  for (int i = 0; i < 4; i++)
    #pragma unroll
    for (int j = 0; j < 4; j++) acc[i][j] = fzero;

  // stage one 128x32 W-tile + 128x32 X-tile into stage buffer `buf` (4 DMAs/thread)
  auto STAGE = [&](int buf, int kb) {
    uint16_t* lw = smem + (size_t)buf*2*128*BK2;
    uint16_t* lx = lw + 128*BK2;
    #pragma unroll
    for (int it = 0; it < 2; it++) {
      int s = t + it*256;              // 512 slots of 16B per tile
      int r = s >> 2, q = s & 3;
      int qm = q ^ (r & 3);            // inverse swizzle on the global side
      uint16_t* ldw = lw + (size_t)(it*256 + w*64)*8;   // wave-uniform base
      uint16_t* ldx = lx + (size_t)(it*256 + w*64)*8;
      gl2lds16(wsrc + (size_t)r*C_ + kb*BK2 + qm*8, ldw);
      gl2lds16(xsrc + (size_t)r*C_ + kb*BK2 + qm*8, ldx);
    }
  };

  STAGE(0, 0);
  STAGE(1, 1);
  asm volatile("s_waitcnt vmcnt(4)" ::: "memory");   // tile 0 landed (tile 1 may fly)
  __builtin_amdgcn_s_barrier();
  __builtin_amdgcn_sched_barrier(0);

  for (int kb = 0; kb < C_/BK2; kb++) {
    int buf = kb % 3;
    if (kb + 2 < C_/BK2) STAGE((kb + 2) % 3, kb + 2);   // flies across the barrier below
    const uint16_t* lw = smem + (size_t)buf*2*128*BK2;
    const uint16_t* lx = lw + 128*BK2;
    short8 af[4], bf[4];
    #pragma unroll
    for (int i = 0; i < 4; i++) {
      int row = wm*64 + i*16 + (lane & 15);
      int q = lane >> 4;
      af[i] = *(const short8*)&lw[row*BK2 + (q ^ (row & 3))*8];
    }
    #pragma unroll
    for (int j = 0; j < 4; j++) {
      int row = wn*64 + j*16 + (lane & 15);
      int q = lane >> 4;
      bf[j] = *(const short8*)&lx[row*BK2 + (q ^ (row & 3))*8];
    }
    #pragma unroll
    for (int i = 0; i < 4; i++)
      #pragma unroll
      for (int j = 0; j < 4; j++)
        acc[i][j] = __builtin_amdgcn_mfma_f32_16x16x32_bf16(af[i], bf[j], acc[i][j], 0, 0, 0);
    if (kb < C_/BK2 - 1) {
      // tile kb+1 (issued >=1 iteration ago) must be landed; newest 4 may fly.
      if (kb + 2 < C_/BK2) asm volatile("s_waitcnt vmcnt(4)" ::: "memory");
      else                 asm volatile("s_waitcnt vmcnt(0)" ::: "memory");
      __builtin_amdgcn_s_barrier();
      __builtin_amdgcn_sched_barrier(0);
    }
  }
  __syncthreads();   // full drain before epilogue aliases the stage buffers

  // epilogue: LDS transpose (aliases stages 0-1 -- safe after final barrier) -> float4 row stores
  int col = lane & 15, quad = lane >> 4;
  int bq = (qt*128) >> 12;
  int p0 = (qt*128) & 4095;
  #pragma unroll
  for (int ph = 0; ph < 2; ph++) {
    if (wm == ph) {
      #pragma unroll
      for (int i = 0; i < 4; i++)
        #pragma unroll
        for (int j = 0; j < 4; j++) {
          int p = wn*64 + j*16 + col;
          #pragma unroll
          for (int r = 0; r < 4; r++) {
            int o2 = i*16 + quad*4 + r;   // local o within 64
            ep[o2*128 + (((p >> 2) ^ (o2 & 7)) << 2) + (p & 3)] = acc[i][j][r];
          }
        }
    }
    __syncthreads();
    #pragma unroll
    for (int i2 = 0; i2 < 8; i2++) {
      int s = t + i2*256;
      int ol = s >> 5, pf = s & 31;
      float4 v = *(const float4*)&ep[ol*128 + ((pf ^ (ol & 7)) << 2)];
      int o = ot*128 + ph*64 + ol;
      float bi = bias[o];
      v.x = fmaxf(v.x + bi, 0.f); v.y = fmaxf(v.y + bi, 0.f);
      v.z = fmaxf(v.z + bi, 0.f); v.w = fmaxf(v.w + bi, 0.f);
      *(float4*)&out[(size_t)bq*C_*HW_ + (size_t)o*HW_ + p0 + pf*4] = v;
    }
    __syncthreads();
  }
}

extern "C" void kernel_launch(void* const* d_in, const int* in_sizes, int n_in,
                              void* d_out, int out_size, void* d_ws, size_t ws_size,
                              hipStream_t stream) {
  (void)in_sizes; (void)n_in; (void)out_size; (void)ws_size;
  const float* x    = (const float*)d_in[0];
  const float* cent = (const float*)d_in[1];
  const float* fw   = (const float*)d_in[2];
  const float* fb   = (const float*)d_in[3];
  float* out = (float*)d_out;
  char* ws = (char*)d_ws;
  size_t off = 0;
  float*    gT    = (float*)(ws + off);    off += (size_t)C_*K_*4;        // 256 KB
  int*      idx   = (int*)(ws + off);      off += (size_t)NPIX*4;         // 128 KB
  int*      count = (int*)(ws + off);      off += (size_t)B_*K_*4;        // 2 KB
  float*    sumx  = (float*)(ws + off);    off += (size_t)B_*K_*C_*4;     // 2 MB (unused; keeps offsets identical)
  float*    cl    = (float*)(ws + off);    off += (size_t)B_*K_*C_*4;     // 2 MB
  float*    clT   = (float*)(ws + off);    off += (size_t)B_*C_*K_*4;     // 2 MB
  float*    cn2   = (float*)(ws + off);    off += (size_t)B_*K_*4 + 8;    // 2 KB (+pad->16B)
  uint16_t* wb    = (uint16_t*)(ws + off); off += (size_t)C_*C_*2;        // 2 MB
  uint16_t* xcal  = (uint16_t*)(ws + off); off += (size_t)NPIX*C_*2;     // 64 MB
  (void)sumx;
  // partial-sum slabs (8 x 2 MB) alias the xcal region: dead once pass_cfinal reads them,
  // and pass_xcal only writes xcal afterwards.
  float* sumxp = (float*)xcal;

  hipMemsetAsync(count, 0, (size_t)B_*K_*4, stream);
  prep_gT   <<<64,   256, 0, stream>>>(cent, gT);
  prep_wb   <<<1024, 256, 0, stream>>>(fw, wb);
  pass_assign<<<512, 256, 0, stream>>>(x, gT, idx, count);
  pass_bins <<<1024, 256, 0, stream>>>(x, idx, sumxp);
  pass_cfinal<<<512, 256, 0, stream>>>(sumxp, count, cl, clT, cn2);
  pass_xcal <<<512,  256, 0, stream>>>(x, idx, cl, clT, cn2, xcal);
  gemm_out  <<<2048, 256, 0, stream>>>(wb, xcal, fb, out);
}